// Round 5
// baseline (624.234 us; speedup 1.0000x reference)
//
#include <hip/hip_runtime.h>

// ---------- helpers ----------
typedef __bf16 bf16x8 __attribute__((ext_vector_type(8)));
typedef float f32x4 __attribute__((ext_vector_type(4)));

__device__ __forceinline__ float bf2f(unsigned short u) {
  union { unsigned int i; float f; } x;
  x.i = ((unsigned int)u) << 16;
  return x.f;
}
__device__ __forceinline__ unsigned short f2bf(float f) {
  union { float f; unsigned int i; } x;
  x.f = f;
  unsigned int u = x.i;
  u += 0x7fffu + ((u >> 16) & 1u);  // RNE
  return (unsigned short)(u >> 16);
}
__device__ __forceinline__ unsigned int fbits(float f) {
  union { float f; unsigned int i; } x; x.f = f; return x.i;
}
// pack two fp32 -> two truncated bf16 in ONE v_perm_b32
__device__ __forceinline__ unsigned int pack_bf16_trunc(float lo, float hi) {
  return __builtin_amdgcn_perm(fbits(hi), fbits(lo), 0x07060302u);
}

// async global->LDS, 16B per lane, LDS dest wave-uniform base (lane auto-offsets by 16B)
__device__ __forceinline__ void load16_to_lds(const void* g, void* l) {
  __builtin_amdgcn_global_load_lds(
      (__attribute__((address_space(1))) void*)const_cast<void*>(g),
      (__attribute__((address_space(3))) void*)l, 16, 0, 0);
}

// packed lower-triangle score buffer: 528 blocks of 128x128 bf16, block-linear.
#define TRI_BLK 16384
#define TRI_NBLK 528
#define PER_BATCH_EL (TRI_NBLK * TRI_BLK)  // 17.3 MB

// ---------- merged cast fp32 -> bf16 (RNE, x4): X then Wq|Wk|Wv contiguous ----------
__global__ __launch_bounds__(256) void cast_all(const float* __restrict__ X,
                                                const float* __restrict__ Wq,
                                                const float* __restrict__ Wk,
                                                const float* __restrict__ Wv,
                                                unsigned short* __restrict__ Xb,
                                                unsigned short* __restrict__ Wb,
                                                int nX4, int nW4 /* per-matrix */) {
  int i = blockIdx.x * 256 + threadIdx.x;
  const float* src;
  unsigned short* dst;
  if (i < nX4) {
    src = X; dst = Xb;
  } else {
    int j = i - nX4;
    int w = j / nW4;          // 0,1,2
    int r = j - w * nW4;
    src = (w == 0) ? Wq : (w == 1) ? Wk : Wv;
    dst = Wb + (long long)w * nW4 * 4;
    i = r;
  }
  float4 f = ((const float4*)src)[i];
  ushort4 o;
  o.x = f2bf(f.x); o.y = f2bf(f.y); o.z = f2bf(f.z); o.w = f2bf(f.w);
  ((ushort4*)dst)[i] = o;
}

// ---------- NT GEMM: C[m][n] = sum_k A[m][k] * B[n][k] ----------
// 128x128 tile, BK=32, 4 waves each own 64x64 (4x4 MFMA 16x16x32 subtiles).
// OPERAND-SWAP: mfma(bfr, af) -> lane l reg r holds C[l&15][(l>>4)*4+r].
// LDS XOR-SWIZZLE: LDS slot (row, c) holds global 16B-chunk c^(row&3) of that row;
// applied on the staging GLOBAL pointer (coalescing intact: same 64B group per
// 4-lane cluster) and undone on the reader address. Breaks the 8-way bank alias
// of the 64B-row layout (rows stride 16 banks) down to 2-way (free).
// MODE 0: proj    -> bf16 out row-major, full K. TGRID=true: by=blockIdx.x (XCD
//                    co-residency for A-strip sharers when x-count ≡ 0 mod 8 partners)
// MODE 1: scores  -> bf16*scale into PACKED-TRI C, grid (528,1,nb); tri index
//                    remapped t=(id&7)*66+(id>>3): each XCD gets 66 contiguous blocks
// MODE 2: PV      -> f32 out, A is PACKED-TRI, K clipped at diagonal; grid (32,8,nb),
//                    by=31-blockIdx.x (deep-first; 8 bx sharers co-resident per XCD)
template <int MODE, bool TGRID = false>
__global__ __launch_bounds__(256) void gemm_nt(const unsigned short* __restrict__ A, int lda,
                                               const unsigned short* __restrict__ B, int ldb,
                                               void* __restrict__ Cv, int ldc, int K, float scale,
                                               long long sA, long long sB, long long sC) {
  int by, bx;
  if constexpr (MODE == 1) {
    int id = blockIdx.x;
    int t = (id & 7) * 66 + (id >> 3);  // XCD-contiguous triangle chunks
    by = (int)((__fsqrt_rn(8.f * t + 1.f) - 1.f) * 0.5f);
    while ((by + 1) * (by + 2) / 2 <= t) ++by;
    while (by * (by + 1) / 2 > t) --by;
    bx = t - by * (by + 1) / 2;
  } else if constexpr (MODE == 2) {
    by = 31 - (int)blockIdx.x;  // deepest K first; bx sharers ≡ same mod 8
    bx = blockIdx.y;
  } else if constexpr (TGRID) {
    by = blockIdx.x;
    bx = blockIdx.y;
  } else {
    by = blockIdx.y;
    bx = blockIdx.x;
  }
  A += (long long)blockIdx.z * sA;
  B += (long long)blockIdx.z * sB;
  if constexpr (MODE == 2) A += (long long)(by * (by + 1) / 2) * TRI_BLK;

  const int rowBase = by * 128;
  const int colBase = bx * 128;
  __shared__ unsigned short As[128 * 32];  // [128][32] el, 64B rows, XOR-swizzled chunks
  __shared__ unsigned short Bs[128 * 32];

  const int tid = threadIdx.x;
  const int wave = tid >> 6;
  const int lane = tid & 63;

  // staging: per wave 2 issues, each covers 16 tile-rows (1024B contiguous LDS)
  const int slot0 = (wave * 2 + 0) * 512;
  const int slot1 = (wave * 2 + 1) * 512;
  const int rr = lane >> 2;                       // row within 16-row group
  const int cSw = ((lane & 3) ^ (rr & 3)) * 8;    // swizzled global chunk (elements)
  const int rS0 = (wave * 2 + 0) * 16 + rr;
  const int rS1 = (wave * 2 + 1) * 16 + rr;
  const unsigned short *aG0, *aG1;
  if constexpr (MODE == 2) {  // packed A: row local, col (k>>7)*TRI_BLK + (k&127)
    aG0 = A + rS0 * 128 + cSw;
    aG1 = A + rS1 * 128 + cSw;
  } else {
    aG0 = A + (size_t)(rowBase + rS0) * lda + cSw;
    aG1 = A + (size_t)(rowBase + rS1) * lda + cSw;
  }
  const unsigned short* bG0 = B + (size_t)(colBase + rS0) * ldb + cSw;
  const unsigned short* bG1 = B + (size_t)(colBase + rS1) * ldb + cSw;

  // compute: wave (wr,wc) owns 64x64 of C
  const int wr = wave >> 1, wc = wave & 1;
  const int fRow = lane & 15;
  // reader chunk g = lane>>4, row&3 = lane&3 -> unswizzle XOR is lane-constant:
  const int fKsw = (((lane >> 4) ^ (lane & 3)) * 8);

  f32x4 acc[4][4];
#pragma unroll
  for (int i = 0; i < 4; ++i)
#pragma unroll
    for (int j = 0; j < 4; ++j) {
      f32x4 z = {0.f, 0.f, 0.f, 0.f};
      acc[i][j] = z;
    }

  const int kEnd = (MODE == 2) ? (by + 1) * 128 : K;
  for (int k0 = 0; k0 < kEnd; k0 += 32) {
    __syncthreads();  // protect LDS from previous iteration's readers
    if constexpr (MODE == 2) {
      int aOff = ((k0 >> 7) << 14) + (k0 & 127);
      load16_to_lds(aG0 + aOff, &As[slot0]);
      load16_to_lds(aG1 + aOff, &As[slot1]);
    } else {
      load16_to_lds(aG0 + k0, &As[slot0]);
      load16_to_lds(aG1 + k0, &As[slot1]);
    }
    load16_to_lds(bG0 + k0, &Bs[slot0]);
    load16_to_lds(bG1 + k0, &Bs[slot1]);
    __syncthreads();

    bf16x8 af[4], bfr[4];
#pragma unroll
    for (int i = 0; i < 4; ++i)
      af[i] = *(const bf16x8*)&As[(64 * wr + 16 * i + fRow) * 32 + fKsw];
#pragma unroll
    for (int j = 0; j < 4; ++j)
      bfr[j] = *(const bf16x8*)&Bs[(64 * wc + 16 * j + fRow) * 32 + fKsw];
#pragma unroll
    for (int i = 0; i < 4; ++i)
#pragma unroll
      for (int j = 0; j < 4; ++j)  // SWAPPED operands -> transposed D fragment layout
        acc[i][j] = __builtin_amdgcn_mfma_f32_16x16x32_bf16(bfr[j], af[i], acc[i][j], 0, 0, 0);
  }

  // epilogue: lane holds C[row = lane&15][cols = (lane>>4)*4 .. +3] per subtile
  const int er = lane & 15;
  const int ec = (lane >> 4) * 4;
  if constexpr (MODE == 2) {
    float* C = (float*)Cv + (long long)blockIdx.z * sC;
#pragma unroll
    for (int i = 0; i < 4; ++i)
#pragma unroll
      for (int j = 0; j < 4; ++j) {
        size_t base = (size_t)(rowBase + 64 * wr + 16 * i + er) * ldc +
                      (size_t)(colBase + 64 * wc + 16 * j + ec);
        *(f32x4*)((float*)C + base) = acc[i][j];
      }
  } else if constexpr (MODE == 1) {
    unsigned short* C = (unsigned short*)Cv + (long long)blockIdx.z * sC +
                        (size_t)(by * (by + 1) / 2 + bx) * TRI_BLK;
#pragma unroll
    for (int i = 0; i < 4; ++i)
#pragma unroll
      for (int j = 0; j < 4; ++j) {
        f32x4 a = acc[i][j];
        a[0] *= scale; a[1] *= scale; a[2] *= scale; a[3] *= scale;
        uint2 p;
        p.x = pack_bf16_trunc(a[0], a[1]);
        p.y = pack_bf16_trunc(a[2], a[3]);
        int row = 64 * wr + 16 * i + er;
        int col = 64 * wc + 16 * j + ec;
        *(uint2*)(C + row * 128 + col) = p;
      }
  } else {
    unsigned short* C = (unsigned short*)Cv + (long long)blockIdx.z * sC;
#pragma unroll
    for (int i = 0; i < 4; ++i)
#pragma unroll
      for (int j = 0; j < 4; ++j) {
        uint2 p;
        p.x = pack_bf16_trunc(acc[i][j][0], acc[i][j][1]);
        p.y = pack_bf16_trunc(acc[i][j][2], acc[i][j][3]);
        size_t base = (size_t)(rowBase + 64 * wr + 16 * i + er) * ldc +
                      (size_t)(colBase + 64 * wc + 16 * j + ec);
        *(uint2*)(C + base) = p;
      }
  }
}

// ---------- in-place causal softmax over PACKED-TRI bf16 scores ----------
__global__ __launch_bounds__(256) void softmax_causal(unsigned short* __restrict__ Sc) {
  const int r = blockIdx.x;
  const int by = r >> 7;
  unsigned short* rowB = Sc + (size_t)blockIdx.y * PER_BATCH_EL +
                         (size_t)(by * (by + 1) / 2) * TRI_BLK + (size_t)(r & 127) * 128;
  const int ncols = (by + 1) << 7;
  const int tid = threadIdx.x;
  const int nIt = (ncols + 2047) >> 11;  // <= 2

  float v[16];
#pragma unroll
  for (int e = 0; e < 16; ++e) v[e] = -1e30f;
  float m = -1e30f;
#pragma unroll 2
  for (int it = 0; it < nIt; ++it) {
    int j0 = (it << 11) + tid * 8;
    if (j0 < ncols) {
      uint4 u = *(const uint4*)(rowB + ((j0 >> 7) << 14) + (j0 & 127));
      const unsigned short* us = (const unsigned short*)&u;
#pragma unroll
      for (int e = 0; e < 8; ++e) {
        float x = bf2f(us[e]);
        x = (j0 + e <= r) ? x : -1e30f;
        v[it * 8 + e] = x;
        m = fmaxf(m, x);
      }
    }
  }
  __shared__ float red[4];
  for (int off = 32; off; off >>= 1) m = fmaxf(m, __shfl_xor(m, off, 64));
  if ((tid & 63) == 0) red[tid >> 6] = m;
  __syncthreads();
  m = fmaxf(fmaxf(red[0], red[1]), fmaxf(red[2], red[3]));
  __syncthreads();

  float s = 0.f;
#pragma unroll
  for (int e = 0; e < 16; ++e) {
    float x = v[e];
    float ex = (x > -1e29f) ? __expf(x - m) : 0.f;
    v[e] = ex;
    s += ex;
  }
  for (int off = 32; off; off >>= 1) s += __shfl_xor(s, off, 64);
  if ((tid & 63) == 0) red[tid >> 6] = s;
  __syncthreads();
  s = red[0] + red[1] + red[2] + red[3];
  float inv = 1.f / s;

#pragma unroll 2
  for (int it = 0; it < nIt; ++it) {
    int j0 = (it << 11) + tid * 8;
    if (j0 < ncols) {
      uint4 o;
      unsigned int* po = (unsigned int*)&o;
#pragma unroll
      for (int e = 0; e < 4; ++e)
        po[e] = pack_bf16_trunc(v[it * 8 + 2 * e] * inv, v[it * 8 + 2 * e + 1] * inv);
      *(uint4*)(rowB + ((j0 >> 7) << 14) + (j0 & 127)) = o;
    }
  }
}

// ---------- launch ----------
extern "C" void kernel_launch(void* const* d_in, const int* in_sizes, int n_in,
                              void* d_out, int out_size, void* d_ws, size_t ws_size,
                              hipStream_t stream) {
  const float* X  = (const float*)d_in[0];
  const float* Wq = (const float*)d_in[1];
  const float* Wk = (const float*)d_in[2];
  const float* Wv = (const float*)d_in[3];
  float* out = (float*)d_out;

  const int Bsz = 4, S = 4096, D = 1024;
  const long long MD = (long long)Bsz * S;  // 16384 rows
  const long long elBig = MD * D;           // 16,777,216

  // ws layout (bf16 el): Wb[3DD] Qb Kb Vt [elBig each] Xb[elBig]; Sc aliases Xb.
  unsigned short* Wb = (unsigned short*)d_ws;
  unsigned short* Qb = Wb + 3LL * D * D;
  unsigned short* Kb = Qb + elBig;
  unsigned short* Vt = Kb + elBig;
  unsigned short* Xb = Vt + elBig;
  unsigned short* Sc = Xb;  // packed-tri, PER_BATCH_EL per batch

  const long long offXb = 3LL * D * D + 3LL * elBig;
  auto needB = [&](int nb) {
    long long tail = (long long)nb * PER_BATCH_EL;
    if (tail < elBig) tail = elBig;
    return (size_t)((offXb + tail) * 2);
  };
  int nb = 1;
  if (ws_size >= needB(4)) nb = 4;        // 176.2 MB
  else if (ws_size >= needB(2)) nb = 2;   // 141.6 MB

  // 1) single merged cast
  {
    int nX4 = (int)(elBig / 4);
    int nW4 = D * D / 4;
    int total = nX4 + 3 * nW4;
    cast_all<<<dim3((total + 255) / 256), 256, 0, stream>>>(X, Wq, Wk, Wv, Xb, Wb, nX4, nW4);
  }

  // 2) Q,K projections (TGRID: s-strip on x -> 8 e-block sharers co-resident per XCD)
  gemm_nt<0, true><<<dim3((unsigned)(MD / 128), D / 128, 2), 256, 0, stream>>>(
      Xb, D, Wb, D, (void*)Qb, D, D, 1.f, 0LL, (long long)D * D, elBig);
  // 3) V transposed: Vt[e][s] = Wv[e,:].X[s,:]  (x=s-strips: X-strip sharers already ≡ mod 8)
  gemm_nt<0, false><<<dim3((unsigned)(MD / 128), D / 128, 1), 256, 0, stream>>>(
      Wb + 2LL * D * D, D, Xb, D, (void*)Vt, (int)MD, D, 1.f, 0LL, 0LL, 0LL);

  // 4) per-batch-group: scores(packed tri) -> softmax -> PV
  const float sscale = 1.0f / 32.0f;  // 1/sqrt(1024)
  for (int b0 = 0; b0 < Bsz; b0 += nb) {
    gemm_nt<1><<<dim3(TRI_NBLK, 1, nb), 256, 0, stream>>>(
        Qb + (long long)b0 * S * D, D, Kb + (long long)b0 * S * D, D, (void*)Sc, 0, D, sscale,
        (long long)S * D, (long long)S * D, (long long)PER_BATCH_EL);
    softmax_causal<<<dim3(S, nb), 256, 0, stream>>>(Sc);
    gemm_nt<2><<<dim3(S / 128, D / 128, nb), 256, 0, stream>>>(
        Sc, 0, Vt + (long long)b0 * S, (int)MD, (void*)(out + (long long)b0 * S * D), D, S, 1.f,
        (long long)PER_BATCH_EL, (long long)S, (long long)S * D);
  }
}

// Round 6
// 575.388 us; speedup vs baseline: 1.0849x; 1.0849x over previous
//
#include <hip/hip_runtime.h>

// ---------- helpers ----------
typedef __bf16 bf16x8 __attribute__((ext_vector_type(8)));
typedef float f32x4 __attribute__((ext_vector_type(4)));

__device__ __forceinline__ float bf2f(unsigned short u) {
  union { unsigned int i; float f; } x;
  x.i = ((unsigned int)u) << 16;
  return x.f;
}
__device__ __forceinline__ unsigned short f2bf(float f) {
  union { float f; unsigned int i; } x;
  x.f = f;
  unsigned int u = x.i;
  u += 0x7fffu + ((u >> 16) & 1u);  // RNE
  return (unsigned short)(u >> 16);
}
__device__ __forceinline__ unsigned int fbits(float f) {
  union { float f; unsigned int i; } x; x.f = f; return x.i;
}
// pack two fp32 -> two truncated bf16 in ONE v_perm_b32
__device__ __forceinline__ unsigned int pack_bf16_trunc(float lo, float hi) {
  return __builtin_amdgcn_perm(fbits(hi), fbits(lo), 0x07060302u);
}

// async global->LDS, 16B per lane, LDS dest wave-uniform base (lane auto-offsets by 16B)
__device__ __forceinline__ void load16_to_lds(const void* g, void* l) {
  __builtin_amdgcn_global_load_lds(
      (__attribute__((address_space(1))) void*)const_cast<void*>(g),
      (__attribute__((address_space(3))) void*)l, 16, 0, 0);
}

// packed lower-triangle score buffer: 528 blocks of 128x128 bf16, block-linear.
#define TRI_BLK 16384
#define TRI_NBLK 528
#define PER_BATCH_EL (TRI_NBLK * TRI_BLK)  // 17.3 MB

// ---------- merged cast fp32 -> bf16 (RNE, x4): X then Wq|Wk|Wv ----------
__global__ __launch_bounds__(256) void cast_all(const float* __restrict__ X,
                                                const float* __restrict__ Wq,
                                                const float* __restrict__ Wk,
                                                const float* __restrict__ Wv,
                                                unsigned short* __restrict__ Xb,
                                                unsigned short* __restrict__ Wb,
                                                int nX4, int nW4 /* per-matrix */) {
  int i = blockIdx.x * 256 + threadIdx.x;
  const float* src;
  unsigned short* dst;
  if (i < nX4) {
    src = X; dst = Xb;
  } else {
    int j = i - nX4;
    int w = j / nW4;          // 0,1,2
    int r = j - w * nW4;
    src = (w == 0) ? Wq : (w == 1) ? Wk : Wv;
    dst = Wb + (long long)w * nW4 * 4;
    i = r;
  }
  float4 f = ((const float4*)src)[i];
  ushort4 o;
  o.x = f2bf(f.x); o.y = f2bf(f.y); o.z = f2bf(f.z); o.w = f2bf(f.w);
  ((ushort4*)dst)[i] = o;
}

// ---------- NT GEMM: C[m][n] = sum_k A[m][k] * B[n][k] ----------
// 128x128 tile, BK=32, 4 waves each own 64x64 (4x4 MFMA 16x16x32 subtiles).
// OPERAND-SWAP: mfma(bfr, af) -> lane l reg r holds C[l&15][(l>>4)*4+r].
// LDS XOR-SWIZZLE v2: LDS slot (row,c) holds global chunk c^((row>>1)&3)
// (bank period of the 64B-row layout is 2 rows). Staging global ptr permuted
// within each row's 64B (coalescing intact); reader unswizzle is lane-constant.
// Reads: 8-way -> 2-way (free, m136).
// MODE 0: proj    -> bf16 out row-major, full K. TGRID: by=blockIdx.x so the 8
//                    W-block sharers of an X-strip (y-dim, stride 128 ≡ 0 mod 8)
//                    are XCD-co-resident.
// MODE 1: scores  -> bf16*scale into PACKED-TRI C, grid (528,1,nb); t=(id&7)*66+(id>>3):
//                    each XCD owns 66 contiguous tri blocks (balanced, L2-local).
// MODE 2: PV      -> f32 out, A PACKED-TRI, K clipped at diagonal. Grid (256,1,nb),
//                    SERPENTINE decode: x=id&7 (XCD), bx=(id>>3)&7, g=id>>6,
//                    by={31-x,16+x,15-x,x}[g] -> per-XCD K-work exactly equal (66),
//                    strip sharers co-resident, deep-first (g-major) dispatch.
template <int MODE, bool TGRID = false>
__global__ __launch_bounds__(256) void gemm_nt(const unsigned short* __restrict__ A, int lda,
                                               const unsigned short* __restrict__ B, int ldb,
                                               void* __restrict__ Cv, int ldc, int K, float scale,
                                               long long sA, long long sB, long long sC) {
  int by, bx;
  if constexpr (MODE == 1) {
    int id = blockIdx.x;
    int t = (id & 7) * 66 + (id >> 3);  // XCD-contiguous triangle chunks
    by = (int)((__fsqrt_rn(8.f * t + 1.f) - 1.f) * 0.5f);
    while ((by + 1) * (by + 2) / 2 <= t) ++by;
    while (by * (by + 1) / 2 > t) --by;
    bx = t - by * (by + 1) / 2;
  } else if constexpr (MODE == 2) {
    int id = blockIdx.x;
    int x = id & 7;
    bx = (id >> 3) & 7;
    int g = id >> 6;  // 0..3, deep rounds first
    by = (g == 0) ? 31 - x : (g == 1) ? 16 + x : (g == 2) ? 15 - x : x;
  } else if constexpr (TGRID) {
    by = blockIdx.x;
    bx = blockIdx.y;
  } else {
    by = blockIdx.y;
    bx = blockIdx.x;
  }
  A += (long long)blockIdx.z * sA;
  B += (long long)blockIdx.z * sB;
  if constexpr (MODE == 2) A += (long long)(by * (by + 1) / 2) * TRI_BLK;

  const int rowBase = by * 128;
  const int colBase = bx * 128;
  __shared__ unsigned short As[128 * 32];  // [128][32] el, 64B rows, XOR-swizzled chunks
  __shared__ unsigned short Bs[128 * 32];

  const int tid = threadIdx.x;
  const int wave = tid >> 6;
  const int lane = tid & 63;

  // staging: per wave 2 issues, each covers 16 tile-rows (1024B contiguous LDS)
  const int slot0 = (wave * 2 + 0) * 512;
  const int slot1 = (wave * 2 + 1) * 512;
  const int rr = lane >> 2;                            // row within 16-row group
  const int cSw = ((lane & 3) ^ ((lane >> 3) & 3)) * 8;  // chunk ^ ((row>>1)&3)
  const int rS0 = (wave * 2 + 0) * 16 + rr;
  const int rS1 = (wave * 2 + 1) * 16 + rr;
  const unsigned short *aG0, *aG1;
  if constexpr (MODE == 2) {  // packed A: row local, col (k>>7)*TRI_BLK + (k&127)
    aG0 = A + rS0 * 128 + cSw;
    aG1 = A + rS1 * 128 + cSw;
  } else {
    aG0 = A + (size_t)(rowBase + rS0) * lda + cSw;
    aG1 = A + (size_t)(rowBase + rS1) * lda + cSw;
  }
  const unsigned short* bG0 = B + (size_t)(colBase + rS0) * ldb + cSw;
  const unsigned short* bG1 = B + (size_t)(colBase + rS1) * ldb + cSw;

  // compute: wave (wr,wc) owns 64x64 of C
  const int wr = wave >> 1, wc = wave & 1;
  const int fRow = lane & 15;
  // reader: row = lane&15 -> (row>>1)&3 = (lane>>1)&3; chunk g = lane>>4
  const int fKsw = (((lane >> 4) ^ ((lane >> 1) & 3)) * 8);

  f32x4 acc[4][4];
#pragma unroll
  for (int i = 0; i < 4; ++i)
#pragma unroll
    for (int j = 0; j < 4; ++j) {
      f32x4 z = {0.f, 0.f, 0.f, 0.f};
      acc[i][j] = z;
    }

  const int kEnd = (MODE == 2) ? (by + 1) * 128 : K;
  for (int k0 = 0; k0 < kEnd; k0 += 32) {
    __syncthreads();  // protect LDS from previous iteration's readers
    if constexpr (MODE == 2) {
      int aOff = ((k0 >> 7) << 14) + (k0 & 127);
      load16_to_lds(aG0 + aOff, &As[slot0]);
      load16_to_lds(aG1 + aOff, &As[slot1]);
    } else {
      load16_to_lds(aG0 + k0, &As[slot0]);
      load16_to_lds(aG1 + k0, &As[slot1]);
    }
    load16_to_lds(bG0 + k0, &Bs[slot0]);
    load16_to_lds(bG1 + k0, &Bs[slot1]);
    __syncthreads();

    bf16x8 af[4], bfr[4];
#pragma unroll
    for (int i = 0; i < 4; ++i)
      af[i] = *(const bf16x8*)&As[(64 * wr + 16 * i + fRow) * 32 + fKsw];
#pragma unroll
    for (int j = 0; j < 4; ++j)
      bfr[j] = *(const bf16x8*)&Bs[(64 * wc + 16 * j + fRow) * 32 + fKsw];
#pragma unroll
    for (int i = 0; i < 4; ++i)
#pragma unroll
      for (int j = 0; j < 4; ++j)  // SWAPPED operands -> transposed D fragment layout
        acc[i][j] = __builtin_amdgcn_mfma_f32_16x16x32_bf16(bfr[j], af[i], acc[i][j], 0, 0, 0);
  }

  // epilogue: lane holds C[row = lane&15][cols = (lane>>4)*4 .. +3] per subtile
  const int er = lane & 15;
  const int ec = (lane >> 4) * 4;
  if constexpr (MODE == 2) {
    float* C = (float*)Cv + (long long)blockIdx.z * sC;
#pragma unroll
    for (int i = 0; i < 4; ++i)
#pragma unroll
      for (int j = 0; j < 4; ++j) {
        size_t base = (size_t)(rowBase + 64 * wr + 16 * i + er) * ldc +
                      (size_t)(colBase + 64 * wc + 16 * j + ec);
        *(f32x4*)((float*)C + base) = acc[i][j];
      }
  } else if constexpr (MODE == 1) {
    unsigned short* C = (unsigned short*)Cv + (long long)blockIdx.z * sC +
                        (size_t)(by * (by + 1) / 2 + bx) * TRI_BLK;
#pragma unroll
    for (int i = 0; i < 4; ++i)
#pragma unroll
      for (int j = 0; j < 4; ++j) {
        f32x4 a = acc[i][j];
        a[0] *= scale; a[1] *= scale; a[2] *= scale; a[3] *= scale;
        uint2 p;
        p.x = pack_bf16_trunc(a[0], a[1]);
        p.y = pack_bf16_trunc(a[2], a[3]);
        int row = 64 * wr + 16 * i + er;
        int col = 64 * wc + 16 * j + ec;
        *(uint2*)(C + row * 128 + col) = p;
      }
  } else {
    unsigned short* C = (unsigned short*)Cv + (long long)blockIdx.z * sC;
#pragma unroll
    for (int i = 0; i < 4; ++i)
#pragma unroll
      for (int j = 0; j < 4; ++j) {
        uint2 p;
        p.x = pack_bf16_trunc(acc[i][j][0], acc[i][j][1]);
        p.y = pack_bf16_trunc(acc[i][j][2], acc[i][j][3]);
        size_t base = (size_t)(rowBase + 64 * wr + 16 * i + er) * ldc +
                      (size_t)(colBase + 64 * wc + 16 * j + ec);
        *(uint2*)(C + base) = p;
      }
  }
}

// ---------- in-place causal softmax over PACKED-TRI bf16 scores ----------
__global__ __launch_bounds__(256) void softmax_causal(unsigned short* __restrict__ Sc) {
  const int r = blockIdx.x;
  const int by = r >> 7;
  unsigned short* rowB = Sc + (size_t)blockIdx.y * PER_BATCH_EL +
                         (size_t)(by * (by + 1) / 2) * TRI_BLK + (size_t)(r & 127) * 128;
  const int ncols = (by + 1) << 7;
  const int tid = threadIdx.x;
  const int nIt = (ncols + 2047) >> 11;  // <= 2

  float v[16];
#pragma unroll
  for (int e = 0; e < 16; ++e) v[e] = -1e30f;
  float m = -1e30f;
#pragma unroll 2
  for (int it = 0; it < nIt; ++it) {
    int j0 = (it << 11) + tid * 8;
    if (j0 < ncols) {
      uint4 u = *(const uint4*)(rowB + ((j0 >> 7) << 14) + (j0 & 127));
      const unsigned short* us = (const unsigned short*)&u;
#pragma unroll
      for (int e = 0; e < 8; ++e) {
        float x = bf2f(us[e]);
        x = (j0 + e <= r) ? x : -1e30f;
        v[it * 8 + e] = x;
        m = fmaxf(m, x);
      }
    }
  }
  __shared__ float red[4];
  for (int off = 32; off; off >>= 1) m = fmaxf(m, __shfl_xor(m, off, 64));
  if ((tid & 63) == 0) red[tid >> 6] = m;
  __syncthreads();
  m = fmaxf(fmaxf(red[0], red[1]), fmaxf(red[2], red[3]));
  __syncthreads();

  float s = 0.f;
#pragma unroll
  for (int e = 0; e < 16; ++e) {
    float x = v[e];
    float ex = (x > -1e29f) ? __expf(x - m) : 0.f;
    v[e] = ex;
    s += ex;
  }
  for (int off = 32; off; off >>= 1) s += __shfl_xor(s, off, 64);
  if ((tid & 63) == 0) red[tid >> 6] = s;
  __syncthreads();
  s = red[0] + red[1] + red[2] + red[3];
  float inv = 1.f / s;

#pragma unroll 2
  for (int it = 0; it < nIt; ++it) {
    int j0 = (it << 11) + tid * 8;
    if (j0 < ncols) {
      uint4 o;
      unsigned int* po = (unsigned int*)&o;
#pragma unroll
      for (int e = 0; e < 4; ++e)
        po[e] = pack_bf16_trunc(v[it * 8 + 2 * e] * inv, v[it * 8 + 2 * e + 1] * inv);
      *(uint4*)(rowB + ((j0 >> 7) << 14) + (j0 & 127)) = o;
    }
  }
}

// ---------- launch ----------
extern "C" void kernel_launch(void* const* d_in, const int* in_sizes, int n_in,
                              void* d_out, int out_size, void* d_ws, size_t ws_size,
                              hipStream_t stream) {
  const float* X  = (const float*)d_in[0];
  const float* Wq = (const float*)d_in[1];
  const float* Wk = (const float*)d_in[2];
  const float* Wv = (const float*)d_in[3];
  float* out = (float*)d_out;

  const int Bsz = 4, S = 4096, D = 1024;
  const long long MD = (long long)Bsz * S;  // 16384 rows
  const long long elBig = MD * D;           // 16,777,216

  // ws layout (bf16 el): Wb[3DD] Qb Kb Vt [elBig each] Xb[elBig]; Sc aliases Xb.
  unsigned short* Wb = (unsigned short*)d_ws;
  unsigned short* Qb = Wb + 3LL * D * D;
  unsigned short* Kb = Qb + elBig;
  unsigned short* Vt = Kb + elBig;
  unsigned short* Xb = Vt + elBig;
  unsigned short* Sc = Xb;  // packed-tri, PER_BATCH_EL per batch

  const long long offXb = 3LL * D * D + 3LL * elBig;
  auto needB = [&](int nb) {
    long long tail = (long long)nb * PER_BATCH_EL;
    if (tail < elBig) tail = elBig;
    return (size_t)((offXb + tail) * 2);
  };
  int nb = 1;
  if (ws_size >= needB(4)) nb = 4;        // 176.2 MB
  else if (ws_size >= needB(2)) nb = 2;   // 141.6 MB

  // 1) single merged cast
  {
    int nX4 = (int)(elBig / 4);
    int nW4 = D * D / 4;
    int total = nX4 + 3 * nW4;
    cast_all<<<dim3((total + 255) / 256), 256, 0, stream>>>(X, Wq, Wk, Wv, Xb, Wb, nX4, nW4);
  }

  // 2) Q,K projections (TGRID: X-strip sharers co-resident per XCD)
  gemm_nt<0, true><<<dim3((unsigned)(MD / 128), D / 128, 2), 256, 0, stream>>>(
      Xb, D, Wb, D, (void*)Qb, D, D, 1.f, 0LL, (long long)D * D, elBig);
  // 3) V transposed: Vt[e][s] = Wv[e,:].X[s,:]  (X-strip sharers ≡ mod 8 already)
  gemm_nt<0, false><<<dim3((unsigned)(MD / 128), D / 128, 1), 256, 0, stream>>>(
      Wb + 2LL * D * D, D, Xb, D, (void*)Vt, (int)MD, D, 1.f, 0LL, 0LL, 0LL);

  // 4) per-batch-group: scores(packed tri) -> softmax -> PV
  const float sscale = 1.0f / 32.0f;  // 1/sqrt(1024)
  for (int b0 = 0; b0 < Bsz; b0 += nb) {
    gemm_nt<1><<<dim3(TRI_NBLK, 1, nb), 256, 0, stream>>>(
        Qb + (long long)b0 * S * D, D, Kb + (long long)b0 * S * D, D, (void*)Sc, 0, D, sscale,
        (long long)S * D, (long long)S * D, (long long)PER_BATCH_EL);
    softmax_causal<<<dim3(S, nb), 256, 0, stream>>>(Sc);
    gemm_nt<2><<<dim3(256, 1, nb), 256, 0, stream>>>(
        Sc, 0, Vt + (long long)b0 * S, (int)MD, (void*)(out + (long long)b0 * S * D), D, S, 1.f,
        (long long)PER_BATCH_EL, (long long)S, (long long)S * D);
  }
}